// Round 9
// baseline (160.584 us; speedup 1.0000x reference)
//
#include <hip/hip_runtime.h>
#include <math.h>

#define NV 4
#define NB 2
#define NC 32
#define ND 32
#define NH 128
#define NW 160
#define NG 8
#define HW (NH*NW)
#define NPIX (NB*NH*NW)
#define FEATSZ (NV*NB*HW*NC)
#define QMAX 128               // window slots per half; LDS = 8*128*8B = 8 KB
#define TBLK (HW/64)           // 320 transpose blocks per (vb)
#define TGRID (TBLK*NV*NB)     // 2560 per tensor

// ---------------------------------------------------------------------------
// proj setup (unchanged)
// ---------------------------------------------------------------------------
__global__ void proj_setup_kernel(const float* __restrict__ proj,
                                  float* __restrict__ pw) {
    int t = blockIdx.x * blockDim.x + threadIdx.x;
    if (t >= NB * NV) return;
    int b = t / NV, v = t % NV;
    const float* Eref = proj + ((b*(NV+1) + 0)*2 + 0)*16;
    const float* Kref = proj + ((b*(NV+1) + 0)*2 + 1)*16;
    const float* Esrc = proj + ((b*(NV+1) + (v+1))*2 + 0)*16;
    const float* Ksrc = proj + ((b*(NV+1) + (v+1))*2 + 1)*16;
    float Mr[12], Ms[12];
    for (int i = 0; i < 3; ++i)
        for (int j = 0; j < 4; ++j) {
            float sr = 0.f, ss = 0.f;
            for (int k = 0; k < 3; ++k) {
                sr += Kref[i*4+k] * Eref[k*4+j];
                ss += Ksrc[i*4+k] * Esrc[k*4+j];
            }
            Mr[i*4+j] = sr; Ms[i*4+j] = ss;
        }
    double A[9], a[3];
    for (int i = 0; i < 3; ++i) {
        for (int j = 0; j < 3; ++j) A[i*3+j] = (double)Mr[i*4+j];
        a[i] = (double)Mr[i*4+3];
    }
    double c00 = A[4]*A[8]-A[5]*A[7];
    double c01 = A[5]*A[6]-A[3]*A[8];
    double c02 = A[3]*A[7]-A[4]*A[6];
    double det = A[0]*c00 + A[1]*c01 + A[2]*c02;
    double id  = 1.0/det;
    double Ai[9];
    Ai[0]=c00*id;                 Ai[1]=(A[2]*A[7]-A[1]*A[8])*id; Ai[2]=(A[1]*A[5]-A[2]*A[4])*id;
    Ai[3]=c01*id;                 Ai[4]=(A[0]*A[8]-A[2]*A[6])*id; Ai[5]=(A[2]*A[3]-A[0]*A[5])*id;
    Ai[6]=c02*id;                 Ai[7]=(A[1]*A[6]-A[0]*A[7])*id; Ai[8]=(A[0]*A[4]-A[1]*A[3])*id;
    double R[9], T[3];
    for (int i = 0; i < 3; ++i)
        for (int j = 0; j < 3; ++j) {
            double s = 0.0;
            for (int k = 0; k < 3; ++k) s += (double)Ms[i*4+k] * Ai[k*3+j];
            R[i*3+j] = s;
        }
    for (int i = 0; i < 3; ++i) {
        double s = (double)Ms[i*4+3];
        for (int k = 0; k < 3; ++k) s -= R[i*3+k]*a[k];
        T[i] = s;
    }
    float* o = pw + (b*NV + v)*12;
    for (int i = 0; i < 9; ++i) o[i]   = (float)R[i];
    for (int i = 0; i < 3; ++i) o[9+i] = (float)T[i];
}

// ---------------------------------------------------------------------------
// Merged prep: [0,TGRID) transpose src; [TGRID,2*TGRID) transpose ref;
// rest: geometry precompute (identical f64 chain + bbox butterfly as R8).
// One launch -> transposes overlap geo work.
// ---------------------------------------------------------------------------
__global__ __launch_bounds__(256) void prep_kernel(
    const float* __restrict__ src_feats,
    const float* __restrict__ ref_feats,
    const float* __restrict__ depth_hypo,
    const float* __restrict__ pw,
    float* __restrict__ srcT,
    float* __restrict__ refT,
    unsigned int* __restrict__ geoXY,
    float2* __restrict__ geoW,
    int4* __restrict__ bboxA)
{
    __shared__ float lds[NC][65];
    int bid = blockIdx.x;
    if (bid < 2*TGRID) {
        int which = bid >= TGRID;
        int tb = which ? bid - TGRID : bid;
        const float* in = which ? ref_feats : src_feats;
        float* outp     = which ? refT : srcT;
        int vb = tb / TBLK;
        int hwbase = (tb % TBLK) * 64;
        int t = threadIdx.x;
        #pragma unroll
        for (int r = 0; r < 8; ++r) {
            int c  = (t >> 6) + r*4;
            int hw = t & 63;
            lds[c][hw] = in[(vb*NC + c)*HW + hwbase + hw];
        }
        __syncthreads();
        #pragma unroll
        for (int r = 0; r < 8; ++r) {
            int c  = t & 31;
            int hw = (t >> 5) + r*8;
            outp[((size_t)vb*HW + hwbase + hw)*NC + c] = lds[c][hw];
        }
        return;
    }
    // ---- geometry part ----
    int tid = (bid - 2*TGRID) * 256 + threadIdx.x;
    int half = tid >> 5;
    int d    = tid & 31;
    if (half >= NV*NPIX) return;
    int v = half / NPIX;
    int p = half - v*NPIX;
    int w = p % NW;
    int h = (p / NW) % NH;
    int b = p / (NW*NH);
    float xf = (float)w, yf = (float)h;
    float depth = depth_hypo[((b*ND + d)*NH + h)*NW + w];

    const float* RT = pw + (b*NV + v)*12;
    double dd  = (double)depth;
    double px_ = ((double)RT[0]*(double)xf + (double)RT[1]*(double)yf + (double)RT[2])*dd + (double)RT[9];
    double py_ = ((double)RT[3]*(double)xf + (double)RT[4]*(double)yf + (double)RT[5])*dd + (double)RT[10];
    double pz_ = ((double)RT[6]*(double)xf + (double)RT[7]*(double)yf + (double)RT[8])*dd + (double)RT[11];
    if (pz_ == 0.0) pz_ = 1e-9;
    double iz  = 1.0 / pz_;
    double pxd = px_*iz, pyd = py_*iz;
    double x0d = floor(pxd), y0d = floor(pyd);
    int x0i = (int)x0d, y0i = (int)y0d;
    float wx = (float)(pxd - x0d), wy = (float)(pyd - y0d);

    int x0s = min(max(x0i, -2), NW);
    int y0s = min(max(y0i, -2), NH);
    geoXY[(size_t)half*ND + d] = ((unsigned int)(unsigned short)(short)x0s)
                               | ((unsigned int)(unsigned short)(short)y0s << 16);
    geoW [(size_t)half*ND + d] = make_float2(wx, wy);

    int xc0 = min(max(x0i,0),NW-1), xc1 = min(max(x0i+1,0),NW-1);
    int yc0 = min(max(y0i,0),NH-1), yc1 = min(max(y0i+1,0),NH-1);
    int mnx = xc0, mxx = xc1, mny = yc0, mxy = yc1;
    #pragma unroll
    for (int mask = 1; mask < 32; mask <<= 1) {
        mnx = min(mnx, __shfl_xor(mnx, mask, 32));
        mxx = max(mxx, __shfl_xor(mxx, mask, 32));
        mny = min(mny, __shfl_xor(mny, mask, 32));
        mxy = max(mxy, __shfl_xor(mxy, mask, 32));
    }
    if (d == 0) bboxA[half] = make_int4(mnx, mxx, mny, mxy);
}

// ---------------------------------------------------------------------------
// Main: wave = pixel; half hi owns views {2hi,2hi+1}.
// S/T staging: per window pixel q, ONE lane computes S(q)=sum_j D_j,
// T(q)=sum_j wr_j*D_j (straight-line 8-chunk dot) -> float2 in LDS.
// Taps: 4 x ds_read_b64 + ~18 VALU. Row index via exact magic-div:
//   M = floor(65536/bw)+1; row=(q*M)>>16 exact for q<=127, bw<=128
//   (error term q*e/65536/bw with e<=2bw: q*e <= 127*256 < 65536).
// ---------------------------------------------------------------------------
__global__ __launch_bounds__(256) void mvs_kernel_g(
    const float* __restrict__ refT,
    const float* __restrict__ srcT,
    const float* __restrict__ depth_hypo,
    const float* __restrict__ w_reg,
    const unsigned int* __restrict__ geoXY,
    const float2* __restrict__ geoW,
    const int4* __restrict__ bboxA,
    float* __restrict__ out)
{
    __shared__ float2 Dlds[8][QMAX];

    int tid = blockIdx.x * 256 + threadIdx.x;
    int lane = threadIdx.x & 63;
    int d  = lane & 31;
    int hi = lane >> 5;
    int p  = tid >> 6;
    if (p >= NPIX) return;
    float2* Dsl = &Dlds[threadIdx.x >> 5][0];
    int sub = lane & 31;

    int w = p % NW;
    int h = (p / NW) % NH;
    int b = p / (NW*NH);
    float depth = depth_hypo[((b*ND + d)*NH + h)*NW + w];

    float wr[NG];
    #pragma unroll
    for (int g = 0; g < NG; ++g) wr[g] = w_reg[g];

    float sv[2], tv[2];

    #pragma unroll
    for (int vv = 0; vv < 2; ++vv) {
        int v = hi*2 + vv;
        size_t half = (size_t)v*NPIX + p;
        unsigned int gxy = geoXY[half*ND + d];
        float2 wxy = geoW[half*ND + d];
        int4 bb = bboxA[half];
        int x0i = (int)(short)(gxy & 0xffffu);
        int y0i = (int)(short)(gxy >> 16);
        int x1i = x0i + 1, y1i = y0i + 1;
        float wx = wxy.x, wy = wxy.y;

        float vx0 = (x0i >= 0 && x0i < NW) ? 1.f : 0.f;
        float vx1 = (x1i >= 0 && x1i < NW) ? 1.f : 0.f;
        float vy0 = (y0i >= 0 && y0i < NH) ? 1.f : 0.f;
        float vy1 = (y1i >= 0 && y1i < NH) ? 1.f : 0.f;
        float w00 = (1.f-wx)*(1.f-wy) * vx0*vy0;
        float w01 = wx*(1.f-wy)       * vx1*vy0;
        float w10 = (1.f-wx)*wy       * vx0*vy1;
        float w11 = wx*wy             * vx1*vy1;
        int xc0 = min(max(x0i,0),NW-1), xc1 = min(max(x1i,0),NW-1);
        int yc0 = min(max(y0i,0),NH-1), yc1 = min(max(y1i,0),NH-1);
        int vb = v*NB + b;

        int mnx = bb.x, mny = bb.z;
        int bw = bb.y - mnx + 1;
        int bh = bb.w - mny + 1;
        int U  = bw * bh;

        const float4* rr = (const float4*)(refT + ((size_t)vb*HW + h*NW + w)*NC);
        float4 r0 = rr[0], r1 = rr[1], r2 = rr[2], r3 = rr[3];
        float4 r4 = rr[4], r5 = rr[5], r6 = rr[6], r7 = rr[7];

        float s = 0.f, t = 0.f;

        if (U <= QMAX) {
            int M = (int)(65536.0f / (float)bw) + 1;
            const float* base = srcT + ((size_t)vb*HW + (size_t)mny*NW + mnx)*NC;
            #pragma unroll
            for (int k = 0; k < 4; ++k) {
                int q = sub + k*32;
                if (q < U) {
                    int row = (q * M) >> 16;
                    int col = q - row*bw;
                    const float4* fp = (const float4*)(base + ((size_t)row*NW + col)*NC);
                    float4 f0 = fp[0], f1 = fp[1], f2 = fp[2], f3 = fp[3];
                    float4 f4 = fp[4], f5 = fp[5], f6 = fp[6], f7 = fp[7];
                    float dj, S, T;
                    dj = f0.x*r0.x; dj = fmaf(f0.y,r0.y,dj); dj = fmaf(f0.z,r0.z,dj); dj = fmaf(f0.w,r0.w,dj);
                    S = dj; T = wr[0]*dj;
                    dj = f1.x*r1.x; dj = fmaf(f1.y,r1.y,dj); dj = fmaf(f1.z,r1.z,dj); dj = fmaf(f1.w,r1.w,dj);
                    S += dj; T = fmaf(wr[1], dj, T);
                    dj = f2.x*r2.x; dj = fmaf(f2.y,r2.y,dj); dj = fmaf(f2.z,r2.z,dj); dj = fmaf(f2.w,r2.w,dj);
                    S += dj; T = fmaf(wr[2], dj, T);
                    dj = f3.x*r3.x; dj = fmaf(f3.y,r3.y,dj); dj = fmaf(f3.z,r3.z,dj); dj = fmaf(f3.w,r3.w,dj);
                    S += dj; T = fmaf(wr[3], dj, T);
                    dj = f4.x*r4.x; dj = fmaf(f4.y,r4.y,dj); dj = fmaf(f4.z,r4.z,dj); dj = fmaf(f4.w,r4.w,dj);
                    S += dj; T = fmaf(wr[4], dj, T);
                    dj = f5.x*r5.x; dj = fmaf(f5.y,r5.y,dj); dj = fmaf(f5.z,r5.z,dj); dj = fmaf(f5.w,r5.w,dj);
                    S += dj; T = fmaf(wr[5], dj, T);
                    dj = f6.x*r6.x; dj = fmaf(f6.y,r6.y,dj); dj = fmaf(f6.z,r6.z,dj); dj = fmaf(f6.w,r6.w,dj);
                    S += dj; T = fmaf(wr[6], dj, T);
                    dj = f7.x*r7.x; dj = fmaf(f7.y,r7.y,dj); dj = fmaf(f7.z,r7.z,dj); dj = fmaf(f7.w,r7.w,dj);
                    S += dj; T = fmaf(wr[7], dj, T);
                    Dsl[q] = make_float2(S, T);
                }
            }
            __builtin_amdgcn_wave_barrier();

            int t00 = (yc0 - mny)*bw + (xc0 - mnx);
            int t01 = (yc0 - mny)*bw + (xc1 - mnx);
            int t10 = (yc1 - mny)*bw + (xc0 - mnx);
            int t11 = (yc1 - mny)*bw + (xc1 - mnx);
            float2 v00 = Dsl[t00];
            float2 v01 = Dsl[t01];
            float2 v10 = Dsl[t10];
            float2 v11 = Dsl[t11];
            s = 0.25f*(w00*v00.x + w01*v01.x + w10*v10.x + w11*v11.x);
            t = 0.25f*(w00*v00.y + w01*v01.y + w10*v10.y + w11*v11.y);
        } else {
            int i00 = yc0*NW+xc0, i01 = yc0*NW+xc1;
            int i10 = yc1*NW+xc0, i11 = yc1*NW+xc1;
            const float4* s00 = (const float4*)(srcT + ((size_t)vb*HW + i00)*NC);
            const float4* s01 = (const float4*)(srcT + ((size_t)vb*HW + i01)*NC);
            const float4* s10 = (const float4*)(srcT + ((size_t)vb*HW + i10)*NC);
            const float4* s11 = (const float4*)(srcT + ((size_t)vb*HW + i11)*NC);
            float4 rf[NG] = {r0,r1,r2,r3,r4,r5,r6,r7};
            #pragma unroll
            for (int j = 0; j < NG; ++j) {
                float4 a00 = s00[j], a01 = s01[j], a10 = s10[j], a11 = s11[j];
                float acc = 0.f;
                float f0 = w00*a00.x + w01*a01.x + w10*a10.x + w11*a11.x;
                acc += f0*rf[j].x;
                float f1 = w00*a00.y + w01*a01.y + w10*a10.y + w11*a11.y;
                acc += f1*rf[j].y;
                float f2 = w00*a00.z + w01*a01.z + w10*a10.z + w11*a11.z;
                acc += f2*rf[j].z;
                float f3 = w00*a00.w + w01*a01.w + w10*a10.w + w11*a11.w;
                acc += f3*rf[j].w;
                float cf = 0.25f*acc;
                s += cf;
                t += cf*wr[j];
            }
        }
        sv[vv] = s; tv[vv] = t;
    }

    float mv0 = sv[0], mv1 = sv[1];
    #pragma unroll
    for (int mask = 1; mask < 32; mask <<= 1) {
        mv0 = fmaxf(mv0, __shfl_xor(mv0, mask, 32));
        mv1 = fmaxf(mv1, __shfl_xor(mv1, mask, 32));
    }
    float Z0 = expf(sv[0] - mv0);
    float Z1 = expf(sv[1] - mv1);
    #pragma unroll
    for (int mask = 1; mask < 32; mask <<= 1) {
        Z0 += __shfl_xor(Z0, mask, 32);
        Z1 += __shfl_xor(Z1, mask, 32);
    }
    float cwA0 = 1.f / Z0;
    float cwA1 = 1.f / Z1;

    float cwB0 = __shfl_xor(cwA0, 32, 64);
    float cwB1 = __shfl_xor(cwA1, 32, 64);
    float tB0  = __shfl_xor(tv[0], 32, 64);
    float tB1  = __shfl_xor(tv[1], 32, 64);

    float cwv[NV], tvv[NV];
    if (hi == 0) {
        cwv[0] = cwA0; tvv[0] = tv[0];
        cwv[1] = cwA1; tvv[1] = tv[1];
        cwv[2] = cwB0; tvv[2] = tB0;
        cwv[3] = cwB1; tvv[3] = tB1;
    } else {
        cwv[0] = cwB0; tvv[0] = tB0;
        cwv[1] = cwB1; tvv[1] = tB1;
        cwv[2] = cwA0; tvv[2] = tv[0];
        cwv[3] = cwA1; tvv[3] = tv[1];
    }
    float logacc = 0.f;
    float cwsum  = 1e-8f;
    #pragma unroll
    for (int v = 0; v < NV; ++v) {
        logacc += cwv[v]*tvv[v];
        cwsum  += cwv[v];
    }

    float logit = logacc / (cwsum + 1e-7f);
    float m2 = logit;
    #pragma unroll
    for (int mask = 1; mask < 32; mask <<= 1)
        m2 = fmaxf(m2, __shfl_xor(m2, mask, 32));
    float e2 = expf(logit - m2);
    float Z2 = e2;
    #pragma unroll
    for (int mask = 1; mask < 32; mask <<= 1)
        Z2 += __shfl_xor(Z2, mask, 32);
    float aw = e2 / Z2;

    float bv2 = aw; int bi = d;
    #pragma unroll
    for (int mask = 1; mask < 32; mask <<= 1) {
        float ov = __shfl_xor(bv2, mask, 32);
        int   oi = __shfl_xor(bi, mask, 32);
        if (ov > bv2 || (ov == bv2 && oi < bi)) { bv2 = ov; bi = oi; }
    }
    float dsel = __shfl(depth, bi, 32);

    if (hi == 0) {
        out[NPIX + ((b*ND + d)*NH + h)*NW + w] = aw;
        if (d == 0) out[p] = dsel;
    }
}

// ---------------------------------------------------------------------------
// Final fallback (original layout) if ws tiny
// ---------------------------------------------------------------------------
__global__ __launch_bounds__(256) void mvs_kernel(
    const float* __restrict__ ref_feats,
    const float* __restrict__ src_feats,
    const float* __restrict__ depth_hypo,
    const float* __restrict__ w_reg,
    const float* __restrict__ pw,
    float* __restrict__ out)
{
    int tid = blockIdx.x * 256 + threadIdx.x;
    int d = threadIdx.x & 31;
    int p = tid >> 5;
    if (p >= NPIX) return;
    int w = p % NW;
    int h = (p / NW) % NH;
    int b = p / (NW*NH);
    float xf = (float)w, yf = (float)h;
    float depth = depth_hypo[((b*ND + d)*NH + h)*NW + w];
    float wr[NG];
    #pragma unroll
    for (int g = 0; g < NG; ++g) wr[g] = w_reg[g];
    float logacc = 0.f;
    float cwsum  = 1e-8f;
    for (int v = 0; v < NV; ++v) {
        const float* RT = pw + (b*NV + v)*12;
        double dd  = (double)depth;
        double px_ = ((double)RT[0]*(double)xf + (double)RT[1]*(double)yf + (double)RT[2])*dd + (double)RT[9];
        double py_ = ((double)RT[3]*(double)xf + (double)RT[4]*(double)yf + (double)RT[5])*dd + (double)RT[10];
        double pz_ = ((double)RT[6]*(double)xf + (double)RT[7]*(double)yf + (double)RT[8])*dd + (double)RT[11];
        if (pz_ == 0.0) pz_ = 1e-9;
        double iz = 1.0/pz_;
        double pxd = px_*iz, pyd = py_*iz;
        double x0d = floor(pxd), y0d = floor(pyd);
        int x0i = (int)x0d, y0i = (int)y0d;
        int x1i = x0i + 1,  y1i = y0i + 1;
        float wx = (float)(pxd - x0d), wy = (float)(pyd - y0d);
        float vx0 = (x0i >= 0 && x0i < NW) ? 1.f : 0.f;
        float vx1 = (x1i >= 0 && x1i < NW) ? 1.f : 0.f;
        float vy0 = (y0i >= 0 && y0i < NH) ? 1.f : 0.f;
        float vy1 = (y1i >= 0 && y1i < NH) ? 1.f : 0.f;
        float w00 = (1.f-wx)*(1.f-wy) * vx0*vy0;
        float w01 = wx*(1.f-wy)       * vx1*vy0;
        float w10 = (1.f-wx)*wy       * vx0*vy1;
        float w11 = wx*wy             * vx1*vy1;
        int xc0 = min(max(x0i,0),NW-1), xc1 = min(max(x1i,0),NW-1);
        int yc0 = min(max(y0i,0),NH-1), yc1 = min(max(y1i,0),NH-1);
        int i00 = yc0*NW+xc0, i01 = yc0*NW+xc1;
        int i10 = yc1*NW+xc0, i11 = yc1*NW+xc1;
        const float* sb = src_feats + ((v*NB + b)*NC)*HW;
        const float* rb = ref_feats + ((v*NB + b)*NC)*HW + h*NW + w;
        float acc[NG];
        #pragma unroll
        for (int g = 0; g < NG; ++g) acc[g] = 0.f;
        #pragma unroll
        for (int c = 0; c < NC; ++c) {
            const float* scp = sb + c*HW;
            float f = w00*scp[i00] + w01*scp[i01] + w10*scp[i10] + w11*scp[i11];
            acc[c>>2] += f * rb[c*HW];
        }
        float s = 0.f, t = 0.f;
        #pragma unroll
        for (int g = 0; g < NG; ++g) {
            float cf = 0.25f*acc[g];
            s += cf;
            t += cf*wr[g];
        }
        float m = s;
        #pragma unroll
        for (int mask = 1; mask < 32; mask <<= 1)
            m = fmaxf(m, __shfl_xor(m, mask, 32));
        float e = expf(s - m);
        float Z = e;
        #pragma unroll
        for (int mask = 1; mask < 32; mask <<= 1)
            Z += __shfl_xor(Z, mask, 32);
        float cw = 1.f / Z;
        logacc += cw * t;
        cwsum  += cw;
    }
    float logit = logacc / (cwsum + 1e-7f);
    float m2 = logit;
    #pragma unroll
    for (int mask = 1; mask < 32; mask <<= 1)
        m2 = fmaxf(m2, __shfl_xor(m2, mask, 32));
    float e2 = expf(logit - m2);
    float Z2 = e2;
    #pragma unroll
    for (int mask = 1; mask < 32; mask <<= 1)
        Z2 += __shfl_xor(Z2, mask, 32);
    float aw = e2 / Z2;
    out[NPIX + ((b*ND + d)*NH + h)*NW + w] = aw;
    float bv = aw; int bi = d;
    #pragma unroll
    for (int mask = 1; mask < 32; mask <<= 1) {
        float ov = __shfl_xor(bv, mask, 32);
        int   oi = __shfl_xor(bi, mask, 32);
        if (ov > bv || (ov == bv && oi < bi)) { bv = ov; bi = oi; }
    }
    float dsel = __shfl(depth, bi, 32);
    if (d == 0) out[p] = dsel;
}

extern "C" void kernel_launch(void* const* d_in, const int* in_sizes, int n_in,
                              void* d_out, int out_size, void* d_ws, size_t ws_size,
                              hipStream_t stream) {
    const float* ref_feats  = (const float*)d_in[0];
    const float* src_feats  = (const float*)d_in[1];
    const float* proj       = (const float*)d_in[2];
    const float* depth_hypo = (const float*)d_in[3];
    const float* w_reg      = (const float*)d_in[4];
    float* out = (float*)d_out;

    size_t featB = (size_t)FEATSZ*sizeof(float);
    size_t geoN  = (size_t)NV*NPIX*ND;
    size_t needG = 2*featB + geoN*sizeof(float2) + geoN*4
                 + (size_t)NV*NPIX*sizeof(int4) + 96*sizeof(float);

    if (ws_size >= needG) {
        char* base = (char*)d_ws;
        float* srcT = (float*)base;                 base += featB;
        float* refT = (float*)base;                 base += featB;
        float2* geoW = (float2*)base;               base += geoN*sizeof(float2);
        unsigned int* geoXY = (unsigned int*)base;  base += geoN*4;
        int4* bboxA = (int4*)base;                  base += (size_t)NV*NPIX*sizeof(int4);
        float* pw = (float*)base;
        hipLaunchKernelGGL(proj_setup_kernel, dim3(1), dim3(64), 0, stream, proj, pw);
        int geoBlocks = (NV*NPIX*32)/256;
        hipLaunchKernelGGL(prep_kernel, dim3(2*TGRID + geoBlocks), dim3(256), 0, stream,
                           src_feats, ref_feats, depth_hypo, pw,
                           srcT, refT, geoXY, geoW, bboxA);
        hipLaunchKernelGGL(mvs_kernel_g, dim3((NPIX*64)/256), dim3(256), 0, stream,
                           refT, srcT, depth_hypo, w_reg, geoXY, geoW, bboxA, out);
    } else {
        float* pw = (float*)d_ws;
        hipLaunchKernelGGL(proj_setup_kernel, dim3(1), dim3(64), 0, stream, proj, pw);
        hipLaunchKernelGGL(mvs_kernel, dim3((NPIX*ND)/256), dim3(256), 0, stream,
                           ref_feats, src_feats, depth_hypo, w_reg, pw, out);
    }
}

// Round 10
// 152.582 us; speedup vs baseline: 1.0524x; 1.0524x over previous
//
#include <hip/hip_runtime.h>
#include <math.h>

#define NV 4
#define NB 2
#define NC 32
#define ND 32
#define NH 128
#define NW 160
#define NG 8
#define HW (NH*NW)
#define NPIX (NB*NH*NW)
#define FEATSZ (NV*NB*HW*NC)
#define QMAX 80                // window slots per half
#define TBLK (HW/64)           // 320 transpose blocks per (vb)
#define TGRID (TBLK*NV*NB)     // 2560 per tensor

// ---------------------------------------------------------------------------
// proj setup (unchanged)
// ---------------------------------------------------------------------------
__global__ void proj_setup_kernel(const float* __restrict__ proj,
                                  float* __restrict__ pw) {
    int t = blockIdx.x * blockDim.x + threadIdx.x;
    if (t >= NB * NV) return;
    int b = t / NV, v = t % NV;
    const float* Eref = proj + ((b*(NV+1) + 0)*2 + 0)*16;
    const float* Kref = proj + ((b*(NV+1) + 0)*2 + 1)*16;
    const float* Esrc = proj + ((b*(NV+1) + (v+1))*2 + 0)*16;
    const float* Ksrc = proj + ((b*(NV+1) + (v+1))*2 + 1)*16;
    float Mr[12], Ms[12];
    for (int i = 0; i < 3; ++i)
        for (int j = 0; j < 4; ++j) {
            float sr = 0.f, ss = 0.f;
            for (int k = 0; k < 3; ++k) {
                sr += Kref[i*4+k] * Eref[k*4+j];
                ss += Ksrc[i*4+k] * Esrc[k*4+j];
            }
            Mr[i*4+j] = sr; Ms[i*4+j] = ss;
        }
    double A[9], a[3];
    for (int i = 0; i < 3; ++i) {
        for (int j = 0; j < 3; ++j) A[i*3+j] = (double)Mr[i*4+j];
        a[i] = (double)Mr[i*4+3];
    }
    double c00 = A[4]*A[8]-A[5]*A[7];
    double c01 = A[5]*A[6]-A[3]*A[8];
    double c02 = A[3]*A[7]-A[4]*A[6];
    double det = A[0]*c00 + A[1]*c01 + A[2]*c02;
    double id  = 1.0/det;
    double Ai[9];
    Ai[0]=c00*id;                 Ai[1]=(A[2]*A[7]-A[1]*A[8])*id; Ai[2]=(A[1]*A[5]-A[2]*A[4])*id;
    Ai[3]=c01*id;                 Ai[4]=(A[0]*A[8]-A[2]*A[6])*id; Ai[5]=(A[2]*A[3]-A[0]*A[5])*id;
    Ai[6]=c02*id;                 Ai[7]=(A[1]*A[6]-A[0]*A[7])*id; Ai[8]=(A[0]*A[4]-A[1]*A[3])*id;
    double R[9], T[3];
    for (int i = 0; i < 3; ++i)
        for (int j = 0; j < 3; ++j) {
            double s = 0.0;
            for (int k = 0; k < 3; ++k) s += (double)Ms[i*4+k] * Ai[k*3+j];
            R[i*3+j] = s;
        }
    for (int i = 0; i < 3; ++i) {
        double s = (double)Ms[i*4+3];
        for (int k = 0; k < 3; ++k) s -= R[i*3+k]*a[k];
        T[i] = s;
    }
    float* o = pw + (b*NV + v)*12;
    for (int i = 0; i < 9; ++i) o[i]   = (float)R[i];
    for (int i = 0; i < 3; ++i) o[9+i] = (float)T[i];
}

// ---------------------------------------------------------------------------
// Merged prep: transposes + geometry precompute (unchanged from R9)
// ---------------------------------------------------------------------------
__global__ __launch_bounds__(256) void prep_kernel(
    const float* __restrict__ src_feats,
    const float* __restrict__ ref_feats,
    const float* __restrict__ depth_hypo,
    const float* __restrict__ pw,
    float* __restrict__ srcT,
    float* __restrict__ refT,
    unsigned int* __restrict__ geoXY,
    float2* __restrict__ geoW,
    int4* __restrict__ bboxA)
{
    __shared__ float lds[NC][65];
    int bid = blockIdx.x;
    if (bid < 2*TGRID) {
        int which = bid >= TGRID;
        int tb = which ? bid - TGRID : bid;
        const float* in = which ? ref_feats : src_feats;
        float* outp     = which ? refT : srcT;
        int vb = tb / TBLK;
        int hwbase = (tb % TBLK) * 64;
        int t = threadIdx.x;
        #pragma unroll
        for (int r = 0; r < 8; ++r) {
            int c  = (t >> 6) + r*4;
            int hw = t & 63;
            lds[c][hw] = in[(vb*NC + c)*HW + hwbase + hw];
        }
        __syncthreads();
        #pragma unroll
        for (int r = 0; r < 8; ++r) {
            int c  = t & 31;
            int hw = (t >> 5) + r*8;
            outp[((size_t)vb*HW + hwbase + hw)*NC + c] = lds[c][hw];
        }
        return;
    }
    int tid = (bid - 2*TGRID) * 256 + threadIdx.x;
    int half = tid >> 5;
    int d    = tid & 31;
    if (half >= NV*NPIX) return;
    int v = half / NPIX;
    int p = half - v*NPIX;
    int w = p % NW;
    int h = (p / NW) % NH;
    int b = p / (NW*NH);
    float xf = (float)w, yf = (float)h;
    float depth = depth_hypo[((b*ND + d)*NH + h)*NW + w];

    const float* RT = pw + (b*NV + v)*12;
    double dd  = (double)depth;
    double px_ = ((double)RT[0]*(double)xf + (double)RT[1]*(double)yf + (double)RT[2])*dd + (double)RT[9];
    double py_ = ((double)RT[3]*(double)xf + (double)RT[4]*(double)yf + (double)RT[5])*dd + (double)RT[10];
    double pz_ = ((double)RT[6]*(double)xf + (double)RT[7]*(double)yf + (double)RT[8])*dd + (double)RT[11];
    if (pz_ == 0.0) pz_ = 1e-9;
    double iz  = 1.0 / pz_;
    double pxd = px_*iz, pyd = py_*iz;
    double x0d = floor(pxd), y0d = floor(pyd);
    int x0i = (int)x0d, y0i = (int)y0d;
    float wx = (float)(pxd - x0d), wy = (float)(pyd - y0d);

    int x0s = min(max(x0i, -2), NW);
    int y0s = min(max(y0i, -2), NH);
    geoXY[(size_t)half*ND + d] = ((unsigned int)(unsigned short)(short)x0s)
                               | ((unsigned int)(unsigned short)(short)y0s << 16);
    geoW [(size_t)half*ND + d] = make_float2(wx, wy);

    int xc0 = min(max(x0i,0),NW-1), xc1 = min(max(x0i+1,0),NW-1);
    int yc0 = min(max(y0i,0),NH-1), yc1 = min(max(y0i+1,0),NH-1);
    int mnx = xc0, mxx = xc1, mny = yc0, mxy = yc1;
    #pragma unroll
    for (int mask = 1; mask < 32; mask <<= 1) {
        mnx = min(mnx, __shfl_xor(mnx, mask, 32));
        mxx = max(mxx, __shfl_xor(mxx, mask, 32));
        mny = min(mny, __shfl_xor(mny, mask, 32));
        mxy = max(mxy, __shfl_xor(mxy, mask, 32));
    }
    if (d == 0) bboxA[half] = make_int4(mnx, mxx, mny, mxy);
}

// ---------------------------------------------------------------------------
// Main: wave = pixel; half hi owns views {2hi,2hi+1}.
// Phase1 (R8-style, coalesced): lane = element n (chunk j = lane&7 fixed);
//   one wave-instr loads 512 contiguous bytes; dj -> Dsc[n] (scalar).
// Phase2 (compaction): lane = q; 2 x ds_read_b128 of Dsc[q*8..+7];
//   S = sum_j dj, T = sum_j wr_j*dj (R9 order) -> ST[q] (float2, conflict-free).
// Taps: 4 x ds_read_b64 + ~18 VALU. All FP identical to R9 (passed, 16.0).
// ---------------------------------------------------------------------------
__global__ __launch_bounds__(256) void mvs_kernel_g(
    const float* __restrict__ refT,
    const float* __restrict__ srcT,
    const float* __restrict__ depth_hypo,
    const float* __restrict__ w_reg,
    const unsigned int* __restrict__ geoXY,
    const float2* __restrict__ geoW,
    const int4* __restrict__ bboxA,
    float* __restrict__ out)
{
    __shared__ float  Dsc[8][QMAX*8];   // scalar chunk-dots, 20 KB
    __shared__ float2 STl[8][QMAX];     // compacted (S,T), 5 KB

    int tid = blockIdx.x * 256 + threadIdx.x;
    int lane = threadIdx.x & 63;
    int d  = lane & 31;
    int hi = lane >> 5;
    int p  = tid >> 6;
    if (p >= NPIX) return;
    int hslot = threadIdx.x >> 5;
    float*  Dh = &Dsc[hslot][0];
    float2* Sh = &STl[hslot][0];
    int sub = lane & 31;
    int jme = sub & 7;

    int w = p % NW;
    int h = (p / NW) % NH;
    int b = p / (NW*NH);
    float depth = depth_hypo[((b*ND + d)*NH + h)*NW + w];

    float wr[NG];
    #pragma unroll
    for (int g = 0; g < NG; ++g) wr[g] = w_reg[g];

    float sv[2], tv[2];

    #pragma unroll
    for (int vv = 0; vv < 2; ++vv) {
        int v = hi*2 + vv;
        size_t half = (size_t)v*NPIX + p;
        unsigned int gxy = geoXY[half*ND + d];
        float2 wxy = geoW[half*ND + d];
        int4 bb = bboxA[half];
        int x0i = (int)(short)(gxy & 0xffffu);
        int y0i = (int)(short)(gxy >> 16);
        int x1i = x0i + 1, y1i = y0i + 1;
        float wx = wxy.x, wy = wxy.y;

        float vx0 = (x0i >= 0 && x0i < NW) ? 1.f : 0.f;
        float vx1 = (x1i >= 0 && x1i < NW) ? 1.f : 0.f;
        float vy0 = (y0i >= 0 && y0i < NH) ? 1.f : 0.f;
        float vy1 = (y1i >= 0 && y1i < NH) ? 1.f : 0.f;
        float w00 = (1.f-wx)*(1.f-wy) * vx0*vy0;
        float w01 = wx*(1.f-wy)       * vx1*vy0;
        float w10 = (1.f-wx)*wy       * vx0*vy1;
        float w11 = wx*wy             * vx1*vy1;
        int xc0 = min(max(x0i,0),NW-1), xc1 = min(max(x1i,0),NW-1);
        int yc0 = min(max(y0i,0),NH-1), yc1 = min(max(y1i,0),NH-1);
        int vb = v*NB + b;

        int mnx = bb.x, mny = bb.z;
        int bw = bb.y - mnx + 1;
        int bh = bb.w - mny + 1;
        int U  = bw * bh;

        const float4* rr = (const float4*)(refT + ((size_t)vb*HW + h*NW + w)*NC);
        float s = 0.f, t = 0.f;

        if (U <= QMAX) {
            // ---- phase 1: coalesced element staging (R8 pattern) ----
            float4 rfj = rr[jme];
            int bw8 = bw * 8;
            for (int yy = 0; yy < bh; ++yy) {
                const float* rowbase = srcT + ((size_t)vb*HW + (size_t)(mny+yy)*NW + mnx)*NC;
                for (int n = sub; n < bw8; n += 32) {
                    float4 f = *(const float4*)(rowbase + 4*n);
                    float dv = f.x*rfj.x;
                    dv = fmaf(f.y, rfj.y, dv);
                    dv = fmaf(f.z, rfj.z, dv);
                    dv = fmaf(f.w, rfj.w, dv);
                    Dh[yy*bw8 + n] = dv;      // element e = q*8 + j
                }
            }
            __builtin_amdgcn_wave_barrier();

            // ---- phase 2: compact 8 djs -> (S,T) per q ----
            #pragma unroll
            for (int k = 0; k < 3; ++k) {     // 3*32 = 96 >= QMAX=80
                int q = sub + k*32;
                if (q < U) {
                    const float4* dp = (const float4*)&Dh[q*8];
                    float4 a = dp[0], c = dp[1];
                    float S = a.x;  S += a.y;  S += a.z;  S += a.w;
                    S += c.x;  S += c.y;  S += c.z;  S += c.w;
                    float T = wr[0]*a.x;
                    T = fmaf(wr[1], a.y, T);
                    T = fmaf(wr[2], a.z, T);
                    T = fmaf(wr[3], a.w, T);
                    T = fmaf(wr[4], c.x, T);
                    T = fmaf(wr[5], c.y, T);
                    T = fmaf(wr[6], c.z, T);
                    T = fmaf(wr[7], c.w, T);
                    Sh[q] = make_float2(S, T);
                }
            }
            __builtin_amdgcn_wave_barrier();

            // ---- taps ----
            int t00 = (yc0 - mny)*bw + (xc0 - mnx);
            int t01 = (yc0 - mny)*bw + (xc1 - mnx);
            int t10 = (yc1 - mny)*bw + (xc0 - mnx);
            int t11 = (yc1 - mny)*bw + (xc1 - mnx);
            float2 v00 = Sh[t00];
            float2 v01 = Sh[t01];
            float2 v10 = Sh[t10];
            float2 v11 = Sh[t11];
            s = 0.25f*(w00*v00.x + w01*v01.x + w10*v10.x + w11*v11.x);
            t = 0.25f*(w00*v00.y + w01*v01.y + w10*v10.y + w11*v11.y);
        } else {
            // ---- fallback: direct per-depth gathers (R9 path) ----
            int i00 = yc0*NW+xc0, i01 = yc0*NW+xc1;
            int i10 = yc1*NW+xc0, i11 = yc1*NW+xc1;
            const float4* s00 = (const float4*)(srcT + ((size_t)vb*HW + i00)*NC);
            const float4* s01 = (const float4*)(srcT + ((size_t)vb*HW + i01)*NC);
            const float4* s10 = (const float4*)(srcT + ((size_t)vb*HW + i10)*NC);
            const float4* s11 = (const float4*)(srcT + ((size_t)vb*HW + i11)*NC);
            #pragma unroll
            for (int j = 0; j < NG; ++j) {
                float4 a00 = s00[j], a01 = s01[j], a10 = s10[j], a11 = s11[j];
                float4 rf  = rr[j];
                float acc = 0.f;
                float f0 = w00*a00.x + w01*a01.x + w10*a10.x + w11*a11.x;
                acc += f0*rf.x;
                float f1 = w00*a00.y + w01*a01.y + w10*a10.y + w11*a11.y;
                acc += f1*rf.y;
                float f2 = w00*a00.z + w01*a01.z + w10*a10.z + w11*a11.z;
                acc += f2*rf.z;
                float f3 = w00*a00.w + w01*a01.w + w10*a10.w + w11*a11.w;
                acc += f3*rf.w;
                float cf = 0.25f*acc;
                s += cf;
                t += cf*wr[j];
            }
        }
        sv[vv] = s; tv[vv] = t;
    }

    float mv0 = sv[0], mv1 = sv[1];
    #pragma unroll
    for (int mask = 1; mask < 32; mask <<= 1) {
        mv0 = fmaxf(mv0, __shfl_xor(mv0, mask, 32));
        mv1 = fmaxf(mv1, __shfl_xor(mv1, mask, 32));
    }
    float Z0 = expf(sv[0] - mv0);
    float Z1 = expf(sv[1] - mv1);
    #pragma unroll
    for (int mask = 1; mask < 32; mask <<= 1) {
        Z0 += __shfl_xor(Z0, mask, 32);
        Z1 += __shfl_xor(Z1, mask, 32);
    }
    float cwA0 = 1.f / Z0;
    float cwA1 = 1.f / Z1;

    float cwB0 = __shfl_xor(cwA0, 32, 64);
    float cwB1 = __shfl_xor(cwA1, 32, 64);
    float tB0  = __shfl_xor(tv[0], 32, 64);
    float tB1  = __shfl_xor(tv[1], 32, 64);

    float cwv[NV], tvv[NV];
    if (hi == 0) {
        cwv[0] = cwA0; tvv[0] = tv[0];
        cwv[1] = cwA1; tvv[1] = tv[1];
        cwv[2] = cwB0; tvv[2] = tB0;
        cwv[3] = cwB1; tvv[3] = tB1;
    } else {
        cwv[0] = cwB0; tvv[0] = tB0;
        cwv[1] = cwB1; tvv[1] = tB1;
        cwv[2] = cwA0; tvv[2] = tv[0];
        cwv[3] = cwA1; tvv[3] = tv[1];
    }
    float logacc = 0.f;
    float cwsum  = 1e-8f;
    #pragma unroll
    for (int v = 0; v < NV; ++v) {
        logacc += cwv[v]*tvv[v];
        cwsum  += cwv[v];
    }

    float logit = logacc / (cwsum + 1e-7f);
    float m2 = logit;
    #pragma unroll
    for (int mask = 1; mask < 32; mask <<= 1)
        m2 = fmaxf(m2, __shfl_xor(m2, mask, 32));
    float e2 = expf(logit - m2);
    float Z2 = e2;
    #pragma unroll
    for (int mask = 1; mask < 32; mask <<= 1)
        Z2 += __shfl_xor(Z2, mask, 32);
    float aw = e2 / Z2;

    float bv2 = aw; int bi = d;
    #pragma unroll
    for (int mask = 1; mask < 32; mask <<= 1) {
        float ov = __shfl_xor(bv2, mask, 32);
        int   oi = __shfl_xor(bi, mask, 32);
        if (ov > bv2 || (ov == bv2 && oi < bi)) { bv2 = ov; bi = oi; }
    }
    float dsel = __shfl(depth, bi, 32);

    if (hi == 0) {
        out[NPIX + ((b*ND + d)*NH + h)*NW + w] = aw;
        if (d == 0) out[p] = dsel;
    }
}

// ---------------------------------------------------------------------------
// Final fallback (original layout) if ws tiny
// ---------------------------------------------------------------------------
__global__ __launch_bounds__(256) void mvs_kernel(
    const float* __restrict__ ref_feats,
    const float* __restrict__ src_feats,
    const float* __restrict__ depth_hypo,
    const float* __restrict__ w_reg,
    const float* __restrict__ pw,
    float* __restrict__ out)
{
    int tid = blockIdx.x * 256 + threadIdx.x;
    int d = threadIdx.x & 31;
    int p = tid >> 5;
    if (p >= NPIX) return;
    int w = p % NW;
    int h = (p / NW) % NH;
    int b = p / (NW*NH);
    float xf = (float)w, yf = (float)h;
    float depth = depth_hypo[((b*ND + d)*NH + h)*NW + w];
    float wr[NG];
    #pragma unroll
    for (int g = 0; g < NG; ++g) wr[g] = w_reg[g];
    float logacc = 0.f;
    float cwsum  = 1e-8f;
    for (int v = 0; v < NV; ++v) {
        const float* RT = pw + (b*NV + v)*12;
        double dd  = (double)depth;
        double px_ = ((double)RT[0]*(double)xf + (double)RT[1]*(double)yf + (double)RT[2])*dd + (double)RT[9];
        double py_ = ((double)RT[3]*(double)xf + (double)RT[4]*(double)yf + (double)RT[5])*dd + (double)RT[10];
        double pz_ = ((double)RT[6]*(double)xf + (double)RT[7]*(double)yf + (double)RT[8])*dd + (double)RT[11];
        if (pz_ == 0.0) pz_ = 1e-9;
        double iz = 1.0/pz_;
        double pxd = px_*iz, pyd = py_*iz;
        double x0d = floor(pxd), y0d = floor(pyd);
        int x0i = (int)x0d, y0i = (int)y0d;
        int x1i = x0i + 1,  y1i = y0i + 1;
        float wx = (float)(pxd - x0d), wy = (float)(pyd - y0d);
        float vx0 = (x0i >= 0 && x0i < NW) ? 1.f : 0.f;
        float vx1 = (x1i >= 0 && x1i < NW) ? 1.f : 0.f;
        float vy0 = (y0i >= 0 && y0i < NH) ? 1.f : 0.f;
        float vy1 = (y1i >= 0 && y1i < NH) ? 1.f : 0.f;
        float w00 = (1.f-wx)*(1.f-wy) * vx0*vy0;
        float w01 = wx*(1.f-wy)       * vx1*vy0;
        float w10 = (1.f-wx)*wy       * vx0*vy1;
        float w11 = wx*wy             * vx1*vy1;
        int xc0 = min(max(x0i,0),NW-1), xc1 = min(max(x1i,0),NW-1);
        int yc0 = min(max(y0i,0),NH-1), yc1 = min(max(y1i,0),NH-1);
        int i00 = yc0*NW+xc0, i01 = yc0*NW+xc1;
        int i10 = yc1*NW+xc0, i11 = yc1*NW+xc1;
        const float* sb = src_feats + ((v*NB + b)*NC)*HW;
        const float* rb = ref_feats + ((v*NB + b)*NC)*HW + h*NW + w;
        float acc[NG];
        #pragma unroll
        for (int g = 0; g < NG; ++g) acc[g] = 0.f;
        #pragma unroll
        for (int c = 0; c < NC; ++c) {
            const float* scp = sb + c*HW;
            float f = w00*scp[i00] + w01*scp[i01] + w10*scp[i10] + w11*scp[i11];
            acc[c>>2] += f * rb[c*HW];
        }
        float s = 0.f, t = 0.f;
        #pragma unroll
        for (int g = 0; g < NG; ++g) {
            float cf = 0.25f*acc[g];
            s += cf;
            t += cf*wr[g];
        }
        float m = s;
        #pragma unroll
        for (int mask = 1; mask < 32; mask <<= 1)
            m = fmaxf(m, __shfl_xor(m, mask, 32));
        float e = expf(s - m);
        float Z = e;
        #pragma unroll
        for (int mask = 1; mask < 32; mask <<= 1)
            Z += __shfl_xor(Z, mask, 32);
        float cw = 1.f / Z;
        logacc += cw * t;
        cwsum  += cw;
    }
    float logit = logacc / (cwsum + 1e-7f);
    float m2 = logit;
    #pragma unroll
    for (int mask = 1; mask < 32; mask <<= 1)
        m2 = fmaxf(m2, __shfl_xor(m2, mask, 32));
    float e2 = expf(logit - m2);
    float Z2 = e2;
    #pragma unroll
    for (int mask = 1; mask < 32; mask <<= 1)
        Z2 += __shfl_xor(Z2, mask, 32);
    float aw = e2 / Z2;
    out[NPIX + ((b*ND + d)*NH + h)*NW + w] = aw;
    float bv = aw; int bi = d;
    #pragma unroll
    for (int mask = 1; mask < 32; mask <<= 1) {
        float ov = __shfl_xor(bv, mask, 32);
        int   oi = __shfl_xor(bi, mask, 32);
        if (ov > bv || (ov == bv && oi < bi)) { bv = ov; bi = oi; }
    }
    float dsel = __shfl(depth, bi, 32);
    if (d == 0) out[p] = dsel;
}

extern "C" void kernel_launch(void* const* d_in, const int* in_sizes, int n_in,
                              void* d_out, int out_size, void* d_ws, size_t ws_size,
                              hipStream_t stream) {
    const float* ref_feats  = (const float*)d_in[0];
    const float* src_feats  = (const float*)d_in[1];
    const float* proj       = (const float*)d_in[2];
    const float* depth_hypo = (const float*)d_in[3];
    const float* w_reg      = (const float*)d_in[4];
    float* out = (float*)d_out;

    size_t featB = (size_t)FEATSZ*sizeof(float);
    size_t geoN  = (size_t)NV*NPIX*ND;
    size_t needG = 2*featB + geoN*sizeof(float2) + geoN*4
                 + (size_t)NV*NPIX*sizeof(int4) + 96*sizeof(float);

    if (ws_size >= needG) {
        char* base = (char*)d_ws;
        float* srcT = (float*)base;                 base += featB;
        float* refT = (float*)base;                 base += featB;
        float2* geoW = (float2*)base;               base += geoN*sizeof(float2);
        unsigned int* geoXY = (unsigned int*)base;  base += geoN*4;
        int4* bboxA = (int4*)base;                  base += (size_t)NV*NPIX*sizeof(int4);
        float* pw = (float*)base;
        hipLaunchKernelGGL(proj_setup_kernel, dim3(1), dim3(64), 0, stream, proj, pw);
        int geoBlocks = (NV*NPIX*32)/256;
        hipLaunchKernelGGL(prep_kernel, dim3(2*TGRID + geoBlocks), dim3(256), 0, stream,
                           src_feats, ref_feats, depth_hypo, pw,
                           srcT, refT, geoXY, geoW, bboxA);
        hipLaunchKernelGGL(mvs_kernel_g, dim3((NPIX*64)/256), dim3(256), 0, stream,
                           refT, srcT, depth_hypo, w_reg, geoXY, geoW, bboxA, out);
    } else {
        float* pw = (float*)d_ws;
        hipLaunchKernelGGL(proj_setup_kernel, dim3(1), dim3(64), 0, stream, proj, pw);
        hipLaunchKernelGGL(mvs_kernel, dim3((NPIX*ND)/256), dim3(256), 0, stream,
                           ref_feats, src_feats, depth_hypo, w_reg, pw, out);
    }
}